// Round 1
// baseline (343.219 us; speedup 1.0000x reference)
//
#include <hip/hip_runtime.h>

// PWLU (channelwise piecewise-linear unit), non-learnable bounds ±2.3.
// x: [B=64, C=256, H=56, W=56] fp32; points: [C,7]; left/right_diffs: [C].
// out[i] = false_points[c, r] + (xn - r) * diffs[c, r]
//   xn = (x - sim_left) / region_len,  r = int(clip(xn, 0, 7.007))
//
// R2 post-mortem: 324us total = ~248us harness 0xAA re-poison fills (2x 822MB
// @ ~124us, 81-83% HBM peak, not controllable) + ~76us kernel vs ~65us
// copy-roofline (411 MB r+w @ 6.3 TB/s).
// R3: kill the per-plane block structure. 1024 blocks x 16 planes:
//   - 16 planes = 12544 f4 = 49*256 exactly -> no tail wave
//   - full 256-channel table built ONCE per block (16 KB LDS), ONE barrier
//     (vs 16384 barriers each draining vmcnt(0))
//   - 49 f4/thread streamed through a 2-deep pipeline, 7 loads in flight
//   - channel from flat idx: (idx*256+tid)/784 -> compiler magic-mul
//     (VALUBusy ~5%, headroom is free); <=2 channels per wave -> the two
//     channels' 8 float2 entries land in disjoint LDS bank halves -> no
//     bank conflicts.
//   - __launch_bounds__(256,4): 4 blocks/CU -> whole 1024-block grid
//     co-resident, equal work per block.

constexpr int NP   = 7;         // n_points
constexpr int NT   = 8;         // table entries = n_points + 1
constexpr int CH   = 256;       // channels
constexpr int HW   = 56 * 56;   // 3136 elements per (b,c) plane
constexpr int HW4  = HW / 4;    // 784 f4 per plane
constexpr int PPB  = 16;        // planes per block
constexpr int F4PB = PPB * HW4; // 12544 f4 per block = 49 * 256
constexpr int UN   = 7;         // inner unroll; 7 pipeline stages * 7 = 49

typedef float f4 __attribute__((ext_vector_type(4)));

__device__ __forceinline__ float pwlu1(float xv, const float2* __restrict__ tc) {
    constexpr float sim_left = -3.0666666666666664f;   // -2.3 - 4.6/6
    constexpr float inv_len  = 1.3043478260869565f;    // 6/4.6
    constexpr float hi       = 7.007f;                  // (n_regions+1)*1.001
    const float xn = (xv - sim_left) * inv_len;
    const int   r  = (int)fminf(fmaxf(xn, 0.0f), hi);
    const float2 t = tc[r];
    return fmaf(xn - (float)r, t.y, t.x);
}

__device__ __forceinline__ f4 pwlu4(f4 v, const float2* __restrict__ tc) {
    f4 o;
    o.x = pwlu1(v.x, tc);
    o.y = pwlu1(v.y, tc);
    o.z = pwlu1(v.z, tc);
    o.w = pwlu1(v.w, tc);
    return o;
}

template<int IT>
__device__ __forceinline__ void load7(f4* v, const f4* __restrict__ xp) {
#pragma unroll
    for (int j = 0; j < UN; ++j)
        v[j] = __builtin_nontemporal_load(xp + (IT * UN + j) * 256);
}

template<int IT>
__device__ __forceinline__ void proc7(const f4* v, f4* __restrict__ op,
                                      const float2* __restrict__ tbl,
                                      int cbase, int tid) {
#pragma unroll
    for (int j = 0; j < UN; ++j) {
        const int idx = IT * UN + j;                          // compile-time
        const int pl  = (int)((unsigned)(idx * 256 + tid) / 784u); // magic-mul
        const float2* tc = tbl + ((cbase + pl) << 3);
        __builtin_nontemporal_store(pwlu4(v[j], tc), op + idx * 256);
    }
}

__global__ __launch_bounds__(256, 4) void pwlu_kernel(
    const f4* __restrict__ x,
    const float* __restrict__ points,
    const float* __restrict__ left_diffs,
    const float* __restrict__ right_diffs,
    f4* __restrict__ out)
{
    __shared__ float2 tbl[CH * NT];   // 16 KB: (false_point, slope) [c][r]

    const int tid = threadIdx.x;
    const size_t base = (size_t)blockIdx.x * F4PB;
    const f4* __restrict__ xp = x + base + tid;
    f4*       __restrict__ op = out + base + tid;

    // Stage-0 loads in flight while the table builds (latency overlap; the
    // barrier's vmcnt(0) drain lands exactly when we need va anyway).
    f4 va[UN], vb[UN];
    load7<0>(va, xp);

    // Build all 256 channels. Entry e = c*8 + r; thread t owns r = t&7 for
    // channels c = 32k + (t>>3). Writes are float2 at e*8 bytes: consecutive
    // lanes -> consecutive banks (2-way alias only, free).
    {
        const int r  = tid & 7;
        const int c0 = tid >> 3;
#pragma unroll
        for (int k = 0; k < NT; ++k) {
            const int c = k * 32 + c0;
            const float* p = points + c * NP;
            float fp, df;
            if (r == 0)       { const float ld = left_diffs[c]; fp = p[0] - ld;  df = ld; }
            else if (r == NP) { fp = p[NP - 1];                  df = right_diffs[c]; }
            else              { const float a = p[r - 1], b = p[r]; fp = a; df = b - a; }
            tbl[c * NT + r] = make_float2(fp, df);
        }
    }
    __syncthreads();

    // c = (blockIdx.x*16 + pl) & 255 = (blockIdx.x & 15)*16 + pl
    const int cbase = (blockIdx.x & (CH / PPB - 1)) * PPB;

    // 2-deep software pipeline: loads of stage k+1 issued before compute of
    // stage k. All indices compile-time -> va/vb stay in VGPRs (no scratch).
    load7<1>(vb, xp); proc7<0>(va, op, tbl, cbase, tid);
    load7<2>(va, xp); proc7<1>(vb, op, tbl, cbase, tid);
    load7<3>(vb, xp); proc7<2>(va, op, tbl, cbase, tid);
    load7<4>(va, xp); proc7<3>(vb, op, tbl, cbase, tid);
    load7<5>(vb, xp); proc7<4>(va, op, tbl, cbase, tid);
    load7<6>(va, xp); proc7<5>(vb, op, tbl, cbase, tid);
    proc7<6>(va, op, tbl, cbase, tid);
}

extern "C" void kernel_launch(void* const* d_in, const int* in_sizes, int n_in,
                              void* d_out, int out_size, void* d_ws, size_t ws_size,
                              hipStream_t stream) {
    const f4*    x  = (const f4*)d_in[0];
    const float* pt = (const float*)d_in[1];
    const float* ld = (const float*)d_in[2];
    const float* rd = (const float*)d_in[3];
    f4*          o  = (f4*)d_out;

    const int planes = in_sizes[0] / HW;   // B*C = 16384
    pwlu_kernel<<<planes / PPB, 256, 0, stream>>>(x, pt, ld, rd, o);
}

// Round 2
// 327.809 us; speedup vs baseline: 1.0470x; 1.0470x over previous
//
#include <hip/hip_runtime.h>

// PWLU (channelwise piecewise-linear unit), non-learnable bounds ±2.3.
// x: [B=64, C=256, H=56, W=56] fp32; points: [C,7]; left/right_diffs: [C].
// out[i] = false_points[c, r] + (xn - r) * diffs[c, r]
//   xn = (x - sim_left) / region_len,  r = int(clip(xn, 0, 7.007))
//
// R3 post-mortem (343us total, kernel ~95us, REGRESSION): 1024 blocks x 16
// planes + __launch_bounds__(256,4) made the grid exactly resident (zero
// over-subscription) and put a 256-channel table build (9KB scattered L2
// reads, 8 divergent iters) on every block's critical path. R2's barriers
// were never the bottleneck -- they were hidden by ~8 resident blocks/CU.
//
// R4: keep tail-freedom + equal work, restore over-subscription, shrink the
// table build:
//   - 6272 blocks x 256 thr x 8 f4/thread = 12,845,056 f4 total, EXACT.
//     Block range (2048 f4) ignores plane boundaries; straddles <= 4 planes.
//   - per-element channel via idx/784 (24-bit magic-mul; VALUBusy ~5%).
//   - table: 4 straddled planes x 8 entries = 256B LDS, built by 32 threads
//     in ONE step; all 8 streaming loads issued before build+barrier.
//   - <=2-way float2 LDS aliasing (free); nontemporal load/store (streaming).

constexpr int NP   = 7;          // n_points
constexpr int HW   = 56 * 56;    // 3136 floats per (b,c) plane
constexpr int HW4  = HW / 4;     // 784 f4 per plane
constexpr int K    = 8;          // f4 per thread
constexpr int F4PB = 256 * K;    // 2048 f4 per block

typedef float f4 __attribute__((ext_vector_type(4)));

__device__ __forceinline__ float pwlu1(float xv, const float2* __restrict__ tc) {
    constexpr float sim_left = -3.0666666666666664f;   // -2.3 - 4.6/6
    constexpr float inv_len  = 1.3043478260869565f;    // 6/4.6
    constexpr float hi       = 7.007f;                  // (n_regions+1)*1.001
    const float xn = (xv - sim_left) * inv_len;
    const int   r  = (int)fminf(fmaxf(xn, 0.0f), hi);
    const float2 t = tc[r];
    return fmaf(xn - (float)r, t.y, t.x);
}

__device__ __forceinline__ f4 pwlu4(f4 v, const float2* __restrict__ tc) {
    f4 o;
    o.x = pwlu1(v.x, tc);
    o.y = pwlu1(v.y, tc);
    o.z = pwlu1(v.z, tc);
    o.w = pwlu1(v.w, tc);
    return o;
}

__global__ __launch_bounds__(256) void pwlu_kernel(
    const f4* __restrict__ x,
    const float* __restrict__ points,
    const float* __restrict__ left_diffs,
    const float* __restrict__ right_diffs,
    f4* __restrict__ out)
{
    __shared__ float2 tbl[4 * 8];   // (false_point, slope) for the <=4 planes

    const int tid = threadIdx.x;
    const unsigned base = (unsigned)blockIdx.x * F4PB;

    // All 8 streaming loads in flight before the table build + barrier.
    const f4* __restrict__ xp = x + base + tid;
    f4 v[K];
#pragma unroll
    for (int j = 0; j < K; ++j)
        v[j] = __builtin_nontemporal_load(xp + j * 256);

    const unsigned plane_lo = base / 784u;   // wave-uniform (scalar div)

    if (tid < 32) {
        const int rel = tid >> 3;            // which straddled plane (0..3)
        const int r   = tid & 7;             // region entry (0..7)
        const int c   = (int)((plane_lo + rel) & 255u);  // plane -> channel
        const float* p = points + c * NP;
        float fp, df;
        if (r == 0)       { const float ld = left_diffs[c]; fp = p[0] - ld;  df = ld; }
        else if (r == NP) { fp = p[NP - 1];                  df = right_diffs[c]; }
        else              { const float a = p[r - 1], b = p[r]; fp = a; df = b - a; }
        tbl[tid] = make_float2(fp, df);
    }
    __syncthreads();

    f4* __restrict__ op = out + base + tid;
#pragma unroll
    for (int j = 0; j < K; ++j) {
        const unsigned idx = base + j * 256u + (unsigned)tid;  // < 2^24
        const int rel = (int)(idx / 784u - plane_lo);          // magic-mul
        const float2* tc = tbl + (rel << 3);
        __builtin_nontemporal_store(pwlu4(v[j], tc), op + j * 256);
    }
}

extern "C" void kernel_launch(void* const* d_in, const int* in_sizes, int n_in,
                              void* d_out, int out_size, void* d_ws, size_t ws_size,
                              hipStream_t stream) {
    const f4*    x  = (const f4*)d_in[0];
    const float* pt = (const float*)d_in[1];
    const float* ld = (const float*)d_in[2];
    const float* rd = (const float*)d_in[3];
    f4*          o  = (f4*)d_out;

    const int planes = in_sizes[0] / HW;            // B*C = 16384
    const int blocks = planes * HW4 / F4PB;         // 6272, exact
    pwlu_kernel<<<blocks, 256, 0, stream>>>(x, pt, ld, rd, o);
}

// Round 3
// 326.753 us; speedup vs baseline: 1.0504x; 1.0032x over previous
//
#include <hip/hip_runtime.h>

// PWLU (channelwise piecewise-linear unit), non-learnable bounds ±2.3.
// x: [B=64, C=256, H=56, W=56] fp32; points: [C,7]; left/right_diffs: [C].
// out[i] = false_points[c, r] + (xn - r) * dists  with per-region (fp, slope).
//
// R4 post-mortem: kernel ~77us (5.34 TB/s) == R2's ~76us despite different
// block structure -> structure is not the limiter. Gap to 6.29 TB/s copy
// ceiling (~65us) remains.
// R5 theory: (1) __syncthreads() emits s_waitcnt vmcnt(0) -> full drain of
// all 8 in-flight loads before any compute; (2) interleaved stores sit in
// the in-order vmcnt retirement queue ahead of later load waits.
// Fix: wave-local table (each wave builds its own 32-entry copy; in-wave
// lgkmcnt ordering only, NO barrier) + compute-all-then-store-all so the
// vmcnt queue is loads-only during the consume phase.

constexpr int NP   = 7;          // n_points
constexpr int HW   = 56 * 56;    // 3136 floats per (b,c) plane
constexpr int HW4  = HW / 4;     // 784 f4 per plane
constexpr int K    = 8;          // f4 per thread
constexpr int F4PB = 256 * K;    // 2048 f4 per block (6272 blocks exact)

typedef float f4 __attribute__((ext_vector_type(4)));

__device__ __forceinline__ float pwlu1(float xv, const float2* __restrict__ tc) {
    constexpr float sim_left = -3.0666666666666664f;   // -2.3 - 4.6/6
    constexpr float inv_len  = 1.3043478260869565f;    // 6/4.6
    constexpr float hi       = 7.007f;                  // (n_regions+1)*1.001
    const float xn = (xv - sim_left) * inv_len;
    const int   r  = (int)fminf(fmaxf(xn, 0.0f), hi);
    const float2 t = tc[r];
    return fmaf(xn - (float)r, t.y, t.x);
}

__device__ __forceinline__ f4 pwlu4(f4 v, const float2* __restrict__ tc) {
    f4 o;
    o.x = pwlu1(v.x, tc);
    o.y = pwlu1(v.y, tc);
    o.z = pwlu1(v.z, tc);
    o.w = pwlu1(v.w, tc);
    return o;
}

__global__ __launch_bounds__(256) void pwlu_kernel(
    const f4* __restrict__ x,
    const float* __restrict__ points,
    const float* __restrict__ left_diffs,
    const float* __restrict__ right_diffs,
    f4* __restrict__ out)
{
    // Per-WAVE table copies: wave w owns tbl[w][rel*8 + r], rel = plane - plane_lo.
    // No __syncthreads needed: producer and consumer are the same wave; the
    // compiler orders ds_write -> lgkmcnt -> ds_read within the wave.
    __shared__ float2 tbl[4][32];

    const int tid  = threadIdx.x;
    const int wv   = tid >> 6;
    const int lane = tid & 63;
    const unsigned base = (unsigned)blockIdx.x * F4PB;

    // All 8 streaming loads in flight before/during the table build.
    const f4* __restrict__ xp = x + base + tid;
    f4 v[K];
#pragma unroll
    for (int j = 0; j < K; ++j)
        v[j] = __builtin_nontemporal_load(xp + j * 256);

    const unsigned plane_lo = base / 784u;   // wave-uniform

    float2* __restrict__ wt = &tbl[wv][0];
    if (lane < 32) {
        const int rel = lane >> 3;           // straddled plane 0..3
        const int r   = lane & 7;            // region entry 0..7
        const int c   = (int)((plane_lo + rel) & 255u);
        const float* p = points + c * NP;
        float fp, df;
        if (r == 0)       { const float ld = left_diffs[c]; fp = p[0] - ld;  df = ld; }
        else if (r == NP) { fp = p[NP - 1];                  df = right_diffs[c]; }
        else              { const float a = p[r - 1], b = p[r]; fp = a; df = b - a; }
        wt[lane] = make_float2(fp, df);
    }
    __builtin_amdgcn_wave_barrier();   // scheduling fence only (no s_barrier)

    // Consume loads in issue order with fine-grained vmcnt waits (no stores
    // in the queue yet), results overwrite v[] in place.
#pragma unroll
    for (int j = 0; j < K; ++j) {
        const unsigned idx = base + j * 256u + (unsigned)tid;   // < 2^24
        const int rel = (int)(idx / 784u - plane_lo);           // magic-mul
        v[j] = pwlu4(v[j], wt + (rel << 3));
    }

    // Store burst at the end: loads-only vmcnt queue during consumption.
    f4* __restrict__ op = out + base + tid;
#pragma unroll
    for (int j = 0; j < K; ++j)
        __builtin_nontemporal_store(v[j], op + j * 256);
}

extern "C" void kernel_launch(void* const* d_in, const int* in_sizes, int n_in,
                              void* d_out, int out_size, void* d_ws, size_t ws_size,
                              hipStream_t stream) {
    const f4*    x  = (const f4*)d_in[0];
    const float* pt = (const float*)d_in[1];
    const float* ld = (const float*)d_in[2];
    const float* rd = (const float*)d_in[3];
    f4*          o  = (f4*)d_out;

    const int planes = in_sizes[0] / HW;            // B*C = 16384
    const int blocks = planes * HW4 / F4PB;         // 6272, exact
    pwlu_kernel<<<blocks, 256, 0, stream>>>(x, pt, ld, rd, o);
}